// Round 2
// baseline (877.576 us; speedup 1.0000x reference)
//
#include <hip/hip_runtime.h>
#include <hip/hip_bf16.h>
#include <math.h>

#define B_ 4
#define L_ 4096
#define D_ 1024
#define M_ (B_*L_)     // 16384
#define N_ 5120        // psi_re | psi_im | phi_re | phi_im | gate (1024 each)
#define K_ 1024
#define CHUNKS 128
#define LC 32          // L_ / CHUNKS
#define PL ((long)M_ * D_)   // plane elements = 16,777,216

// ws layout (bytes):
//   [0        , 33554432)  xb (bf16 x)              -- dead after GEMM
//   [33554432 , 44040192)  wb (bf16 W concat)       -- dead after GEMM
//   [44040192 , 211812352) raw5: 5 bf16 planes [g][M][D]
//   overlay after GEMM: E at [0, 4194304), carry at [4194304, 8388608)
#define WS_NEEDED 211812352ull

typedef __attribute__((ext_vector_type(8))) short bf16x8;
typedef __attribute__((ext_vector_type(4))) float f32x4;

// ---------------- K0: convert x and concat(W_psi, W_phi, W_gate) to bf16 ----------------
__global__ void convert_kernel(const float* __restrict__ x,
                               const float* __restrict__ Wpsi,
                               const float* __restrict__ Wphi,
                               const float* __restrict__ Wgate,
                               __hip_bfloat16* __restrict__ xb,
                               __hip_bfloat16* __restrict__ wb) {
    long i0 = (long)blockIdx.x * blockDim.x + threadIdx.x;
    long stride = (long)gridDim.x * blockDim.x;
    const long nx = (long)M_ * K_;
    for (long j = i0; j < nx; j += stride) xb[j] = __float2bfloat16(x[j]);
    const long nW1 = 2048L * 1024, nW2 = 2048L * 1024, nW3 = 1024L * 1024;
    for (long j = i0; j < nW1; j += stride) wb[j] = __float2bfloat16(Wpsi[j]);
    for (long j = i0; j < nW2; j += stride) wb[nW1 + j] = __float2bfloat16(Wphi[j]);
    for (long j = i0; j < nW3; j += stride) wb[nW1 + nW2 + j] = __float2bfloat16(Wgate[j]);
}

// ---------------- K1: bf16 MFMA GEMM -> planar bf16 planes ----------------
// Block = 256 threads = 4 waves in 2x2; each wave computes 64x64 (4x4 tiles of 16x16x32).
// A lane layout: A[m = lane&15][k = (lane>>4)*8 + j]; B^T same with n = lane&15.
// C/D: col = lane&15, row = (lane>>4)*4 + reg.
__global__ __launch_bounds__(256) void gemm_kernel(const __hip_bfloat16* __restrict__ xb,
                                                   const __hip_bfloat16* __restrict__ wb,
                                                   const float* __restrict__ b_psi,
                                                   const float* __restrict__ b_phi,
                                                   const float* __restrict__ b_gate,
                                                   __hip_bfloat16* __restrict__ raw5) {
    const int wave = threadIdx.x >> 6;
    const int lane = threadIdx.x & 63;
    const int row  = lane & 15;
    const int quad = lane >> 4;
    const int m_base = blockIdx.x * 128 + (wave >> 1) * 64;
    const int n_base = blockIdx.y * 128 + (wave & 1) * 64;

    f32x4 acc[4][4] = {};
    const __hip_bfloat16* ap = xb + (long)(m_base + row) * K_ + quad * 8;
    const __hip_bfloat16* bp = wb + (long)(n_base + row) * K_ + quad * 8;

    for (int k0 = 0; k0 < K_; k0 += 32) {
        bf16x8 a[4], b[4];
#pragma unroll
        for (int i = 0; i < 4; i++) {
            a[i] = *(const bf16x8*)(ap + (long)i * 16 * K_ + k0);
            b[i] = *(const bf16x8*)(bp + (long)i * 16 * K_ + k0);
        }
#pragma unroll
        for (int mi = 0; mi < 4; mi++)
#pragma unroll
            for (int ni = 0; ni < 4; ni++)
                acc[mi][ni] = __builtin_amdgcn_mfma_f32_16x16x32_bf16(a[mi], b[ni], acc[mi][ni], 0, 0, 0);
    }

#pragma unroll
    for (int mi = 0; mi < 4; mi++) {
#pragma unroll
        for (int ni = 0; ni < 4; ni++) {
            int n = n_base + ni * 16 + row;
            float bias = (n < 2048) ? b_psi[n] : (n < 4096) ? b_phi[n - 2048] : b_gate[n - 4096];
            int g = n >> 10, d = n & 1023;
            __hip_bfloat16* pl = raw5 + (long)g * PL;
#pragma unroll
            for (int r = 0; r < 4; r++) {
                int m = m_base + mi * 16 + quad * 4 + r;
                pl[(long)m * D_ + d] = __float2bfloat16(acc[mi][ni][r] + bias);
            }
        }
    }
}

// ---------------- K2: U = sigmoid(gate) * psi  (in-place on planes 0,1) ----------------
__global__ void gate_kernel(__hip_bfloat16* __restrict__ raw5) {
    long i0 = (long)blockIdx.x * blockDim.x + threadIdx.x;
    long stride = (long)gridDim.x * blockDim.x;
    for (long i = i0; i < PL; i += stride) {
        float g = __bfloat162float(raw5[4 * PL + i]);
        float sg = 1.f / (1.f + expf(-g));
        raw5[i]      = __float2bfloat16(sg * __bfloat162float(raw5[i]));
        raw5[PL + i] = __float2bfloat16(sg * __bfloat162float(raw5[PL + i]));
    }
}

// ---------------- K3: per-chunk local scan (zero init), store chunk-end state ----------------
__global__ __launch_bounds__(1024) void scan1_kernel(const __hip_bfloat16* __restrict__ raw5,
                                                     const float* __restrict__ omega,
                                                     const float* __restrict__ log_gamma,
                                                     const float* __restrict__ dtp,
                                                     float2* __restrict__ E) {
    const int d = threadIdx.x;
    const int c = blockIdx.x;
    const int b = blockIdx.y;
    const float dt = fabsf(dtp[0]);
    const float decay = expf(-expf(log_gamma[d]) * dt);
    const float ang = omega[d] * dt;
    const float ar = decay * cosf(ang), ai = decay * sinf(ang);

    const __hip_bfloat16* Ure = raw5;
    const __hip_bfloat16* Uim = raw5 + PL;
    long base = (long)(b * L_ + c * LC) * D_ + d;

    float hr = 0.f, hi = 0.f;
    for (int i = 0; i < LC; i++) {
        float ur = __bfloat162float(Ure[base + (long)i * D_]);
        float ui = __bfloat162float(Uim[base + (long)i * D_]);
        float nhr = ar * hr - ai * hi + ur;
        float nhi = ar * hi + ai * hr + ui;
        hr = nhr; hi = nhi;
    }
    E[((long)c * B_ + b) * D_ + d] = make_float2(hr, hi);
}

// ---------------- K4: sequential carry scan across chunks ----------------
__global__ void carry_kernel(const float2* __restrict__ E,
                             const float* __restrict__ omega,
                             const float* __restrict__ log_gamma,
                             const float* __restrict__ dtp,
                             float2* __restrict__ carry) {
    int t = blockIdx.x * blockDim.x + threadIdx.x;  // 0 .. B_*D_-1
    int b = t >> 10, d = t & 1023;
    const float dt = fabsf(dtp[0]);
    const float decay = expf(-expf(log_gamma[d]) * dt * (float)LC);
    const float ang = omega[d] * dt * (float)LC;
    const float Ar = decay * cosf(ang), Ai = decay * sinf(ang);
    float sr = 0.f, si = 0.f;
    for (int c = 0; c < CHUNKS; c++) {
        long idx = ((long)c * B_ + b) * D_ + d;
        carry[idx] = make_float2(sr, si);
        float2 e = E[idx];
        float nr = e.x + Ar * sr - Ai * si;
        float ni = e.y + Ar * si + Ai * sr;
        sr = nr; si = ni;
    }
}

// ---------------- K5: replay scan with carry + standardize over D + output ----------------
__global__ __launch_bounds__(1024) void scan2_kernel(const __hip_bfloat16* __restrict__ raw5,
                                                     const float2* __restrict__ carry,
                                                     const float* __restrict__ omega,
                                                     const float* __restrict__ log_gamma,
                                                     const float* __restrict__ dtp,
                                                     float* __restrict__ out) {
    const int d = threadIdx.x;
    const int c = blockIdx.x;
    const int b = blockIdx.y;
    const float dt = fabsf(dtp[0]);
    const float decay = expf(-expf(log_gamma[d]) * dt);
    const float ang = omega[d] * dt;
    const float ar = decay * cosf(ang), ai = decay * sinf(ang);

    float2 h0 = carry[((long)c * B_ + b) * D_ + d];
    float hr = h0.x, hi = h0.y;

    __shared__ float red[16][4];
    __shared__ float stats[4];
    const int lane = threadIdx.x & 63, wv = threadIdx.x >> 6;

    const __hip_bfloat16* Ure = raw5;
    const __hip_bfloat16* Uim = raw5 + PL;
    const __hip_bfloat16* Pre = raw5 + 2 * PL;
    const __hip_bfloat16* Pim = raw5 + 3 * PL;
    long base = (long)(b * L_ + c * LC) * D_ + d;

    for (int i = 0; i < LC; i++) {
        long idx = base + (long)i * D_;
        float ur = __bfloat162float(Ure[idx]);
        float ui = __bfloat162float(Uim[idx]);
        float nhr = ar * hr - ai * hi + ur;
        float nhi = ar * hi + ai * hr + ui;
        hr = nhr; hi = nhi;

        float s0 = hr, s1 = hr * hr, s2 = hi, s3 = hi * hi;
        for (int off = 32; off; off >>= 1) {
            s0 += __shfl_down(s0, off);
            s1 += __shfl_down(s1, off);
            s2 += __shfl_down(s2, off);
            s3 += __shfl_down(s3, off);
        }
        if (lane == 0) { red[wv][0] = s0; red[wv][1] = s1; red[wv][2] = s2; red[wv][3] = s3; }
        __syncthreads();
        if (wv == 0 && lane < 4) {
            float t = 0.f;
#pragma unroll
            for (int w = 0; w < 16; w++) t += red[w][lane];
            stats[lane] = t;
        }
        __syncthreads();
        float mean_r = stats[0] * (1.f / D_);
        float var_r  = stats[1] * (1.f / D_) - mean_r * mean_r;
        float mean_i = stats[2] * (1.f / D_);
        float var_i  = stats[3] * (1.f / D_) - mean_i * mean_i;
        float inv_r = 1.f / (sqrtf(fmaxf(var_r, 0.f)) + 1e-6f);
        float inv_i = 1.f / (sqrtf(fmaxf(var_i, 0.f)) + 1e-6f);
        float pr = __bfloat162float(Pre[idx]);
        float pi = __bfloat162float(Pim[idx]);
        out[idx] = (hr - mean_r) * inv_r * pr + (hi - mean_i) * inv_i * pi;
    }
}

// ---------------- launch ----------------
extern "C" void kernel_launch(void* const* d_in, const int* in_sizes, int n_in,
                              void* d_out, int out_size, void* d_ws, size_t ws_size,
                              hipStream_t stream) {
    (void)in_sizes; (void)n_in; (void)out_size;
    if (ws_size < WS_NEEDED) return;  // fail loudly via absmax, not a memory fault

    const float* x         = (const float*)d_in[0];
    const float* omega     = (const float*)d_in[1];
    const float* log_gamma = (const float*)d_in[2];
    const float* dt        = (const float*)d_in[3];
    const float* W_psi     = (const float*)d_in[4];
    const float* b_psi     = (const float*)d_in[5];
    const float* W_phi     = (const float*)d_in[6];
    const float* b_phi     = (const float*)d_in[7];
    const float* W_gate    = (const float*)d_in[8];
    const float* b_gate    = (const float*)d_in[9];

    char* ws = (char*)d_ws;
    __hip_bfloat16* xb   = (__hip_bfloat16*)(ws);
    __hip_bfloat16* wb   = (__hip_bfloat16*)(ws + 33554432);
    __hip_bfloat16* raw5 = (__hip_bfloat16*)(ws + 44040192);
    float2* E     = (float2*)(ws);             // overlays xb (dead after GEMM)
    float2* carry = (float2*)(ws + 4194304);   // still within old xb region
    float* out = (float*)d_out;

    convert_kernel<<<2048, 256, 0, stream>>>(x, W_psi, W_phi, W_gate, xb, wb);
    gemm_kernel<<<dim3(M_ / 128, N_ / 128), 256, 0, stream>>>(xb, wb, b_psi, b_phi, b_gate, raw5);
    gate_kernel<<<4096, 256, 0, stream>>>(raw5);
    scan1_kernel<<<dim3(CHUNKS, B_), 1024, 0, stream>>>(raw5, omega, log_gamma, dt, E);
    carry_kernel<<<16, 256, 0, stream>>>(E, omega, log_gamma, dt, carry);
    scan2_kernel<<<dim3(CHUNKS, B_), 1024, 0, stream>>>(raw5, carry, omega, log_gamma, dt, out);
}

// Round 3
// 510.177 us; speedup vs baseline: 1.7201x; 1.7201x over previous
//
#include <hip/hip_runtime.h>
#include <hip/hip_bf16.h>
#include <math.h>

#define B_ 4
#define L_ 4096
#define D_ 1024
#define M_ (B_*L_)     // 16384
#define N_ 5120        // psi_re | psi_im | phi_re | phi_im | gate (1024 each)
#define K_ 1024
#define CHUNKS 128
#define LC 32          // L_ / CHUNKS
#define PL ((long)M_ * D_)   // plane elements = 16,777,216

// ws layout (bytes):
//   [0        , 33554432)  xb (bf16 x)              -- dead after GEMM
//   [33554432 , 44040192)  wb (bf16 W concat)       -- dead after GEMM
//   [44040192 , 211812352) raw5: 5 bf16 planes [g][M][D]
//   overlay after GEMM: E at [0, 4194304), carry at [4194304, 8388608)
#define WS_NEEDED 211812352ull

typedef __attribute__((ext_vector_type(8))) short bf16x8;
typedef __attribute__((ext_vector_type(4))) float f32x4;

// ---------------- K0: convert x and concat(W_psi, W_phi, W_gate) to bf16 ----------------
__global__ void convert_kernel(const float* __restrict__ x,
                               const float* __restrict__ Wpsi,
                               const float* __restrict__ Wphi,
                               const float* __restrict__ Wgate,
                               __hip_bfloat16* __restrict__ xb,
                               __hip_bfloat16* __restrict__ wb) {
    long i0 = (long)blockIdx.x * blockDim.x + threadIdx.x;
    long stride = (long)gridDim.x * blockDim.x;
    const long nx = (long)M_ * K_;
    for (long j = i0; j < nx; j += stride) xb[j] = __float2bfloat16(x[j]);
    const long nW1 = 2048L * 1024, nW2 = 2048L * 1024, nW3 = 1024L * 1024;
    for (long j = i0; j < nW1; j += stride) wb[j] = __float2bfloat16(Wpsi[j]);
    for (long j = i0; j < nW2; j += stride) wb[nW1 + j] = __float2bfloat16(Wphi[j]);
    for (long j = i0; j < nW3; j += stride) wb[nW1 + nW2 + j] = __float2bfloat16(Wgate[j]);
}

// ---------------- K1: bf16 MFMA GEMM, LDS-staged (m97 structure) ----------------
// Block 256 = 4 waves (2x2), wave computes 64x64 via 4x4 MFMA 16x16x32 tiles.
// BM=BN=128, BK=64. LDS tiles As/Bs: [128 rows][64 k], row = 8 chunks of 8 bf16 (16B).
// Chunk p of row r holds GLOBAL chunk p^(r&7)  (XOR swizzle; applied on the global
// source address because global_load_lds's LDS side is fixed wave-uniform base + lane*16).
#define BM 128
#define BN 128
#define BK 64
__global__ __launch_bounds__(256) void gemm_kernel(const __hip_bfloat16* __restrict__ xb,
                                                   const __hip_bfloat16* __restrict__ wb,
                                                   const float* __restrict__ b_psi,
                                                   const float* __restrict__ b_phi,
                                                   const float* __restrict__ b_gate,
                                                   __hip_bfloat16* __restrict__ raw5) {
    __shared__ __hip_bfloat16 As[BM * BK];   // 16 KB
    __shared__ __hip_bfloat16 Bs[BN * BK];   // 16 KB

    const int tid  = threadIdx.x;
    const int wave = tid >> 6;
    const int lane = tid & 63;
    const int row16 = lane & 15;
    const int quad  = lane >> 4;
    const int m_blk = blockIdx.x * BM;
    const int n_blk = blockIdx.y * BN;
    const int m_off = (wave >> 1) * 64;
    const int n_off = (wave & 1) * 64;

    const int sub_r = lane >> 3;   // 0..7 (row within an 8-row staging stripe)
    const int ci    = lane & 7;    // LDS chunk position within row

    f32x4 acc[4][4] = {};

    for (int k0 = 0; k0 < K_; k0 += BK) {
        __syncthreads();  // previous compute must finish before overwrite
#pragma unroll
        for (int j2 = 0; j2 < 4; j2++) {
            int j  = wave * 4 + j2;          // staging stripe 0..15 (8 rows each)
            int r  = j * 8 + sub_r;          // tile row 0..127
            int gc = ci ^ (r & 7);           // global chunk for this LDS slot
            const __hip_bfloat16* ga = xb + (long)(m_blk + r) * K_ + k0 + gc * 8;
            const __hip_bfloat16* gb = wb + (long)(n_blk + r) * K_ + k0 + gc * 8;
            __builtin_amdgcn_global_load_lds(
                (const __attribute__((address_space(1))) void*)ga,
                (__attribute__((address_space(3))) void*)((char*)As + j * 1024),
                16, 0, 0);
            __builtin_amdgcn_global_load_lds(
                (const __attribute__((address_space(1))) void*)gb,
                (__attribute__((address_space(3))) void*)((char*)Bs + j * 1024),
                16, 0, 0);
        }
        __syncthreads();  // staging visible to all waves

#pragma unroll
        for (int ks = 0; ks < 2; ks++) {
            bf16x8 a[4], b[4];
            int c = ks * 4 + quad;           // global chunk wanted (8 elems)
#pragma unroll
            for (int t = 0; t < 4; t++) {
                int ra = m_off + t * 16 + row16;
                a[t] = *(const bf16x8*)((const char*)As + ra * 128 + ((c ^ (ra & 7)) * 16));
                int rb = n_off + t * 16 + row16;
                b[t] = *(const bf16x8*)((const char*)Bs + rb * 128 + ((c ^ (rb & 7)) * 16));
            }
#pragma unroll
            for (int mi = 0; mi < 4; mi++)
#pragma unroll
                for (int ni = 0; ni < 4; ni++)
                    acc[mi][ni] = __builtin_amdgcn_mfma_f32_16x16x32_bf16(a[mi], b[ni], acc[mi][ni], 0, 0, 0);
        }
    }

#pragma unroll
    for (int mi = 0; mi < 4; mi++) {
#pragma unroll
        for (int ni = 0; ni < 4; ni++) {
            int n = n_blk + n_off + ni * 16 + row16;
            float bias = (n < 2048) ? b_psi[n] : (n < 4096) ? b_phi[n - 2048] : b_gate[n - 4096];
            int g = n >> 10, d = n & 1023;
            __hip_bfloat16* pl = raw5 + (long)g * PL;
#pragma unroll
            for (int r = 0; r < 4; r++) {
                int m = m_blk + m_off + mi * 16 + quad * 4 + r;
                pl[(long)m * D_ + d] = __float2bfloat16(acc[mi][ni][r] + bias);
            }
        }
    }
}

// ---------------- K3: per-chunk local scan (gate fused), store chunk-end state ----------------
__global__ __launch_bounds__(1024) void scan1_kernel(const __hip_bfloat16* __restrict__ raw5,
                                                     const float* __restrict__ omega,
                                                     const float* __restrict__ log_gamma,
                                                     const float* __restrict__ dtp,
                                                     float2* __restrict__ E) {
    const int d = threadIdx.x;
    const int c = blockIdx.x;
    const int b = blockIdx.y;
    const float dt = fabsf(dtp[0]);
    const float decay = expf(-expf(log_gamma[d]) * dt);
    const float ang = omega[d] * dt;
    const float ar = decay * cosf(ang), ai = decay * sinf(ang);

    const __hip_bfloat16* Pre = raw5;
    const __hip_bfloat16* Pim = raw5 + PL;
    const __hip_bfloat16* Gt  = raw5 + 4 * PL;
    long base = (long)(b * L_ + c * LC) * D_ + d;

    float hr = 0.f, hi = 0.f;
    for (int i = 0; i < LC; i++) {
        long idx = base + (long)i * D_;
        float sg = 1.f / (1.f + expf(-__bfloat162float(Gt[idx])));
        float ur = sg * __bfloat162float(Pre[idx]);
        float ui = sg * __bfloat162float(Pim[idx]);
        float nhr = ar * hr - ai * hi + ur;
        float nhi = ar * hi + ai * hr + ui;
        hr = nhr; hi = nhi;
    }
    E[((long)c * B_ + b) * D_ + d] = make_float2(hr, hi);
}

// ---------------- K4: sequential carry scan across chunks ----------------
__global__ void carry_kernel(const float2* __restrict__ E,
                             const float* __restrict__ omega,
                             const float* __restrict__ log_gamma,
                             const float* __restrict__ dtp,
                             float2* __restrict__ carry) {
    int t = blockIdx.x * blockDim.x + threadIdx.x;  // 0 .. B_*D_-1
    int b = t >> 10, d = t & 1023;
    const float dt = fabsf(dtp[0]);
    const float decay = expf(-expf(log_gamma[d]) * dt * (float)LC);
    const float ang = omega[d] * dt * (float)LC;
    const float Ar = decay * cosf(ang), Ai = decay * sinf(ang);
    float sr = 0.f, si = 0.f;
    for (int c = 0; c < CHUNKS; c++) {
        long idx = ((long)c * B_ + b) * D_ + d;
        carry[idx] = make_float2(sr, si);
        float2 e = E[idx];
        float nr = e.x + Ar * sr - Ai * si;
        float ni = e.y + Ar * si + Ai * sr;
        sr = nr; si = ni;
    }
}

// ---------------- K5: replay scan (gate fused) + standardize over D + output ----------------
__global__ __launch_bounds__(1024) void scan2_kernel(const __hip_bfloat16* __restrict__ raw5,
                                                     const float2* __restrict__ carry,
                                                     const float* __restrict__ omega,
                                                     const float* __restrict__ log_gamma,
                                                     const float* __restrict__ dtp,
                                                     float* __restrict__ out) {
    const int d = threadIdx.x;
    const int c = blockIdx.x;
    const int b = blockIdx.y;
    const float dt = fabsf(dtp[0]);
    const float decay = expf(-expf(log_gamma[d]) * dt);
    const float ang = omega[d] * dt;
    const float ar = decay * cosf(ang), ai = decay * sinf(ang);

    float2 h0 = carry[((long)c * B_ + b) * D_ + d];
    float hr = h0.x, hi = h0.y;

    __shared__ float red[16][4];
    __shared__ float stats[4];
    const int lane = threadIdx.x & 63, wv = threadIdx.x >> 6;

    const __hip_bfloat16* Ure = raw5;
    const __hip_bfloat16* Uim = raw5 + PL;
    const __hip_bfloat16* Pre = raw5 + 2 * PL;
    const __hip_bfloat16* Pim = raw5 + 3 * PL;
    const __hip_bfloat16* Gt  = raw5 + 4 * PL;
    long base = (long)(b * L_ + c * LC) * D_ + d;

    for (int i = 0; i < LC; i++) {
        long idx = base + (long)i * D_;
        float sg = 1.f / (1.f + expf(-__bfloat162float(Gt[idx])));
        float ur = sg * __bfloat162float(Ure[idx]);
        float ui = sg * __bfloat162float(Uim[idx]);
        float nhr = ar * hr - ai * hi + ur;
        float nhi = ar * hi + ai * hr + ui;
        hr = nhr; hi = nhi;

        float s0 = hr, s1 = hr * hr, s2 = hi, s3 = hi * hi;
        for (int off = 32; off; off >>= 1) {
            s0 += __shfl_down(s0, off);
            s1 += __shfl_down(s1, off);
            s2 += __shfl_down(s2, off);
            s3 += __shfl_down(s3, off);
        }
        if (lane == 0) { red[wv][0] = s0; red[wv][1] = s1; red[wv][2] = s2; red[wv][3] = s3; }
        __syncthreads();
        if (wv == 0 && lane < 4) {
            float t = 0.f;
#pragma unroll
            for (int w = 0; w < 16; w++) t += red[w][lane];
            stats[lane] = t;
        }
        __syncthreads();
        float mean_r = stats[0] * (1.f / D_);
        float var_r  = stats[1] * (1.f / D_) - mean_r * mean_r;
        float mean_i = stats[2] * (1.f / D_);
        float var_i  = stats[3] * (1.f / D_) - mean_i * mean_i;
        float inv_r = 1.f / (sqrtf(fmaxf(var_r, 0.f)) + 1e-6f);
        float inv_i = 1.f / (sqrtf(fmaxf(var_i, 0.f)) + 1e-6f);
        float pr = __bfloat162float(Pre[idx]);
        float pi = __bfloat162float(Pim[idx]);
        out[idx] = (hr - mean_r) * inv_r * pr + (hi - mean_i) * inv_i * pi;
    }
}

// ---------------- launch ----------------
extern "C" void kernel_launch(void* const* d_in, const int* in_sizes, int n_in,
                              void* d_out, int out_size, void* d_ws, size_t ws_size,
                              hipStream_t stream) {
    (void)in_sizes; (void)n_in; (void)out_size;
    if (ws_size < WS_NEEDED) return;  // fail loudly via absmax, not a memory fault

    const float* x         = (const float*)d_in[0];
    const float* omega     = (const float*)d_in[1];
    const float* log_gamma = (const float*)d_in[2];
    const float* dt        = (const float*)d_in[3];
    const float* W_psi     = (const float*)d_in[4];
    const float* b_psi     = (const float*)d_in[5];
    const float* W_phi     = (const float*)d_in[6];
    const float* b_phi     = (const float*)d_in[7];
    const float* W_gate    = (const float*)d_in[8];
    const float* b_gate    = (const float*)d_in[9];

    char* ws = (char*)d_ws;
    __hip_bfloat16* xb   = (__hip_bfloat16*)(ws);
    __hip_bfloat16* wb   = (__hip_bfloat16*)(ws + 33554432);
    __hip_bfloat16* raw5 = (__hip_bfloat16*)(ws + 44040192);
    float2* E     = (float2*)(ws);             // overlays xb (dead after GEMM)
    float2* carry = (float2*)(ws + 4194304);   // still within old xb region
    float* out = (float*)d_out;

    convert_kernel<<<2048, 256, 0, stream>>>(x, W_psi, W_phi, W_gate, xb, wb);
    gemm_kernel<<<dim3(M_ / BM, N_ / BN), 256, 0, stream>>>(xb, wb, b_psi, b_phi, b_gate, raw5);
    scan1_kernel<<<dim3(CHUNKS, B_), 1024, 0, stream>>>(raw5, omega, log_gamma, dt, E);
    carry_kernel<<<16, 256, 0, stream>>>(E, omega, log_gamma, dt, carry);
    scan2_kernel<<<dim3(CHUNKS, B_), 1024, 0, stream>>>(raw5, carry, omega, log_gamma, dt, out);
}

// Round 4
// 485.029 us; speedup vs baseline: 1.8093x; 1.0518x over previous
//
#include <hip/hip_runtime.h>
#include <hip/hip_bf16.h>
#include <math.h>

#define B_ 4
#define L_ 4096
#define D_ 1024
#define M_ (B_*L_)     // 16384
#define N_ 5120        // psi_re | psi_im | phi_re | phi_im | gate (1024 each)
#define K_ 1024
#define CHUNKS 128
#define LC 32          // L_ / CHUNKS
#define PL ((long)M_ * D_)   // plane elements = 16,777,216

// ws layout (bytes):
//   [0        , 33554432)  xb (bf16 x)              -- dead after GEMM
//   [33554432 , 44040192)  wb (bf16 W concat)       -- dead after GEMM
//   [44040192 , 211812352) raw5: 5 bf16 planes [g][M][D]
//       planes: 0=psi_re->H_re  1=psi_im->H_im  2=phi_re  3=phi_im  4=gate
//   overlay after GEMM (inside dead xb region):
//       E at [0, 4194304), carry at [4194304, 8388608), apow at [8388608, 8650752)
#define WS_NEEDED 211812352ull

typedef __attribute__((ext_vector_type(8))) short bf16x8;
typedef __attribute__((ext_vector_type(4))) float f32x4;

__device__ inline float b2f(short s) {
    unsigned u = ((unsigned)(unsigned short)s) << 16;
    float f; __builtin_memcpy(&f, &u, 4); return f;
}

// ---------------- K0: convert x and concat(W_psi, W_phi, W_gate) to bf16 (vectorized) ----
__device__ inline void cvt4(const float4* __restrict__ src, ushort* __restrict__ dst, long j) {
    float4 v = src[j];
    __hip_bfloat16 a = __float2bfloat16(v.x), b = __float2bfloat16(v.y),
                   c = __float2bfloat16(v.z), d = __float2bfloat16(v.w);
    ushort4 o = { *(ushort*)&a, *(ushort*)&b, *(ushort*)&c, *(ushort*)&d };
    *(ushort4*)(dst + j * 4) = o;
}

__global__ void convert_kernel(const float* __restrict__ x,
                               const float* __restrict__ Wpsi,
                               const float* __restrict__ Wphi,
                               const float* __restrict__ Wgate,
                               ushort* __restrict__ xb,
                               ushort* __restrict__ wb) {
    long i0 = (long)blockIdx.x * blockDim.x + threadIdx.x;
    long stride = (long)gridDim.x * blockDim.x;
    const long nx4 = ((long)M_ * K_) >> 2;           // 4,194,304
    for (long j = i0; j < nx4; j += stride) cvt4((const float4*)x, xb, j);
    const long nW14 = (2048L * 1024) >> 2, nW34 = (1024L * 1024) >> 2;
    for (long j = i0; j < nW14; j += stride) cvt4((const float4*)Wpsi, wb, j);
    for (long j = i0; j < nW14; j += stride) cvt4((const float4*)Wphi, wb + 2048L * 1024, j);
    for (long j = i0; j < nW34; j += stride) cvt4((const float4*)Wgate, wb + 4096L * 1024, j);
}

// ---------------- K1: bf16 MFMA GEMM, LDS-staged (m97 structure) ----------------
#define BM 128
#define BN 128
#define BK 64
__global__ __launch_bounds__(256) void gemm_kernel(const __hip_bfloat16* __restrict__ xb,
                                                   const __hip_bfloat16* __restrict__ wb,
                                                   const float* __restrict__ b_psi,
                                                   const float* __restrict__ b_phi,
                                                   const float* __restrict__ b_gate,
                                                   __hip_bfloat16* __restrict__ raw5) {
    __shared__ __hip_bfloat16 As[BM * BK];   // 16 KB
    __shared__ __hip_bfloat16 Bs[BN * BK];   // 16 KB

    const int tid  = threadIdx.x;
    const int wave = tid >> 6;
    const int lane = tid & 63;
    const int row16 = lane & 15;
    const int quad  = lane >> 4;
    const int m_blk = blockIdx.x * BM;
    const int n_blk = blockIdx.y * BN;
    const int m_off = (wave >> 1) * 64;
    const int n_off = (wave & 1) * 64;

    const int sub_r = lane >> 3;   // 0..7
    const int ci    = lane & 7;    // LDS chunk position within row

    f32x4 acc[4][4] = {};

    for (int k0 = 0; k0 < K_; k0 += BK) {
        __syncthreads();
#pragma unroll
        for (int j2 = 0; j2 < 4; j2++) {
            int j  = wave * 4 + j2;
            int r  = j * 8 + sub_r;
            int gc = ci ^ (r & 7);
            const __hip_bfloat16* ga = xb + (long)(m_blk + r) * K_ + k0 + gc * 8;
            const __hip_bfloat16* gb = wb + (long)(n_blk + r) * K_ + k0 + gc * 8;
            __builtin_amdgcn_global_load_lds(
                (const __attribute__((address_space(1))) void*)ga,
                (__attribute__((address_space(3))) void*)((char*)As + j * 1024),
                16, 0, 0);
            __builtin_amdgcn_global_load_lds(
                (const __attribute__((address_space(1))) void*)gb,
                (__attribute__((address_space(3))) void*)((char*)Bs + j * 1024),
                16, 0, 0);
        }
        __syncthreads();

#pragma unroll
        for (int ks = 0; ks < 2; ks++) {
            bf16x8 a[4], b[4];
            int c = ks * 4 + quad;
#pragma unroll
            for (int t = 0; t < 4; t++) {
                int ra = m_off + t * 16 + row16;
                a[t] = *(const bf16x8*)((const char*)As + ra * 128 + ((c ^ (ra & 7)) * 16));
                int rb = n_off + t * 16 + row16;
                b[t] = *(const bf16x8*)((const char*)Bs + rb * 128 + ((c ^ (rb & 7)) * 16));
            }
#pragma unroll
            for (int mi = 0; mi < 4; mi++)
#pragma unroll
                for (int ni = 0; ni < 4; ni++)
                    acc[mi][ni] = __builtin_amdgcn_mfma_f32_16x16x32_bf16(a[mi], b[ni], acc[mi][ni], 0, 0, 0);
        }
    }

#pragma unroll
    for (int mi = 0; mi < 4; mi++) {
#pragma unroll
        for (int ni = 0; ni < 4; ni++) {
            int n = n_blk + n_off + ni * 16 + row16;
            float bias = (n < 2048) ? b_psi[n] : (n < 4096) ? b_phi[n - 2048] : b_gate[n - 4096];
            int g = n >> 10, d = n & 1023;
            __hip_bfloat16* pl = raw5 + (long)g * PL;
#pragma unroll
            for (int r = 0; r < 4; r++) {
                int m = m_blk + m_off + mi * 16 + quad * 4 + r;
                pl[(long)m * D_ + d] = __float2bfloat16(acc[mi][ni][r] + bias);
            }
        }
    }
}

// ---------------- K2: local scan (gate fused), H_local written in place over psi ------
__global__ __launch_bounds__(1024) void scan1_kernel(__hip_bfloat16* raw5,   // no restrict: in-place
                                                     const float* __restrict__ omega,
                                                     const float* __restrict__ log_gamma,
                                                     const float* __restrict__ dtp,
                                                     float2* __restrict__ E) {
    const int d = threadIdx.x;
    const int c = blockIdx.x;
    const int b = blockIdx.y;
    const float dt = fabsf(dtp[0]);
    const float decay = expf(-expf(log_gamma[d]) * dt);
    const float ang = omega[d] * dt;
    const float ar = decay * cosf(ang), ai = decay * sinf(ang);

    __hip_bfloat16* Pre = raw5;
    __hip_bfloat16* Pim = raw5 + PL;
    const __hip_bfloat16* Gt = raw5 + 4 * PL;
    long base = (long)(b * L_ + c * LC) * D_ + d;

    float hr = 0.f, hi = 0.f;
    for (int i = 0; i < LC; i++) {
        long idx = base + (long)i * D_;
        float sg = 1.f / (1.f + expf(-__bfloat162float(Gt[idx])));
        float ur = sg * __bfloat162float(Pre[idx]);
        float ui = sg * __bfloat162float(Pim[idx]);
        float nhr = ar * hr - ai * hi + ur;
        float nhi = ar * hi + ai * hr + ui;
        hr = nhr; hi = nhi;
        Pre[idx] = __float2bfloat16(hr);   // H_local overwrites psi (same thread, same idx)
        Pim[idx] = __float2bfloat16(hi);
    }
    E[((long)c * B_ + b) * D_ + d] = make_float2(hr, hi);
}

// ---------------- K3: Apow[i][d] = a_d^(i+1) ----------------
__global__ void apow_kernel(const float* __restrict__ omega,
                            const float* __restrict__ log_gamma,
                            const float* __restrict__ dtp,
                            float2* __restrict__ apow) {
    int t = blockIdx.x * blockDim.x + threadIdx.x;  // 0..32767
    int i = t >> 10, d = t & 1023;
    float dt = fabsf(dtp[0]);
    float e = expf(-expf(log_gamma[d]) * dt * (float)(i + 1));
    float ang = omega[d] * dt * (float)(i + 1);
    apow[t] = make_float2(e * cosf(ang), e * sinf(ang));
}

// ---------------- K4: carry via Kogge-Stone over chunks (one block per (b,d)) --------
__global__ __launch_bounds__(128) void carry_kernel(const float2* __restrict__ E,
                                                    const float* __restrict__ omega,
                                                    const float* __restrict__ log_gamma,
                                                    const float* __restrict__ dtp,
                                                    float2* __restrict__ carry) {
    __shared__ float2 sh[CHUNKS];
    const int c = threadIdx.x;
    const int bd = blockIdx.x;           // b*1024 + d
    const int b = bd >> 10, d = bd & 1023;
    const float dt = fabsf(dtp[0]);
    const float gd = expf(log_gamma[d]);
    const float wd = omega[d];

    float2 v = E[((long)c * B_ + b) * D_ + d];
    sh[c] = v;
    __syncthreads();
#pragma unroll
    for (int s = 1; s < CHUNKS; s <<= 1) {
        float2 prev;
        bool has = (c >= s);
        if (has) prev = sh[c - s];
        __syncthreads();
        if (has) {
            float t = dt * (float)LC * (float)s;
            float dec = expf(-gd * t);
            float ang = wd * t;
            float Ar = dec * cosf(ang), Ai = dec * sinf(ang);
            v.x += Ar * prev.x - Ai * prev.y;
            v.y += Ar * prev.y + Ai * prev.x;
            sh[c] = v;
        }
        __syncthreads();
    }
    float2 outv = (c == 0) ? make_float2(0.f, 0.f) : sh[c - 1];  // carry[c] = t_{c-1}
    carry[((long)c * B_ + b) * D_ + d] = outv;
}

// ---------------- K5: fixup + standardize + output (one wave per row, no barriers) ----
__global__ __launch_bounds__(256) void finish_kernel(const __hip_bfloat16* __restrict__ raw5,
                                                     const float2* __restrict__ carry,
                                                     const float2* __restrict__ apow,
                                                     float* __restrict__ out) {
    const int wv = threadIdx.x >> 6, lane = threadIdx.x & 63;
    const int r = blockIdx.x * 4 + wv;       // row 0..16383
    const int l = r & (L_ - 1);
    const int b = r >> 12;
    const int c = l >> 5, i = l & 31;
    const int d0 = lane * 16;
    const long base = (long)r * D_ + d0;

    const __hip_bfloat16* Hre = raw5;
    const __hip_bfloat16* Him = raw5 + PL;
    const __hip_bfloat16* Pre = raw5 + 2 * PL;
    const __hip_bfloat16* Pim = raw5 + 3 * PL;
    const float2* cr = carry + ((long)c * B_ + b) * D_ + d0;
    const float2* ap = apow + (long)i * D_ + d0;

    bf16x8 hre[2], him[2];
    hre[0] = *(const bf16x8*)(Hre + base);     hre[1] = *(const bf16x8*)(Hre + base + 8);
    him[0] = *(const bf16x8*)(Him + base);     him[1] = *(const bf16x8*)(Him + base + 8);

    float hr[16], hi[16];
    float s0 = 0.f, s1 = 0.f, s2 = 0.f, s3 = 0.f;
#pragma unroll
    for (int j = 0; j < 16; j++) {
        float2 cv = cr[j];
        float2 av = ap[j];
        float fr = av.x * cv.x - av.y * cv.y;
        float fi = av.x * cv.y + av.y * cv.x;
        float xr = b2f(hre[j >> 3][j & 7]) + fr;
        float xi = b2f(him[j >> 3][j & 7]) + fi;
        hr[j] = xr; hi[j] = xi;
        s0 += xr; s1 += xr * xr; s2 += xi; s3 += xi * xi;
    }
#pragma unroll
    for (int m = 1; m < 64; m <<= 1) {
        s0 += __shfl_xor(s0, m);
        s1 += __shfl_xor(s1, m);
        s2 += __shfl_xor(s2, m);
        s3 += __shfl_xor(s3, m);
    }
    float mean_r = s0 * (1.f / D_);
    float var_r  = s1 * (1.f / D_) - mean_r * mean_r;
    float mean_i = s2 * (1.f / D_);
    float var_i  = s3 * (1.f / D_) - mean_i * mean_i;
    float inv_r = 1.f / (sqrtf(fmaxf(var_r, 0.f)) + 1e-6f);
    float inv_i = 1.f / (sqrtf(fmaxf(var_i, 0.f)) + 1e-6f);

    bf16x8 pre[2], pim[2];
    pre[0] = *(const bf16x8*)(Pre + base);     pre[1] = *(const bf16x8*)(Pre + base + 8);
    pim[0] = *(const bf16x8*)(Pim + base);     pim[1] = *(const bf16x8*)(Pim + base + 8);

    float o[16];
#pragma unroll
    for (int j = 0; j < 16; j++)
        o[j] = (hr[j] - mean_r) * inv_r * b2f(pre[j >> 3][j & 7])
             + (hi[j] - mean_i) * inv_i * b2f(pim[j >> 3][j & 7]);
#pragma unroll
    for (int q = 0; q < 4; q++)
        *(float4*)(out + base + q * 4) = make_float4(o[q*4], o[q*4+1], o[q*4+2], o[q*4+3]);
}

// ---------------- launch ----------------
extern "C" void kernel_launch(void* const* d_in, const int* in_sizes, int n_in,
                              void* d_out, int out_size, void* d_ws, size_t ws_size,
                              hipStream_t stream) {
    (void)in_sizes; (void)n_in; (void)out_size;
    if (ws_size < WS_NEEDED) return;

    const float* x         = (const float*)d_in[0];
    const float* omega     = (const float*)d_in[1];
    const float* log_gamma = (const float*)d_in[2];
    const float* dt        = (const float*)d_in[3];
    const float* W_psi     = (const float*)d_in[4];
    const float* b_psi     = (const float*)d_in[5];
    const float* W_phi     = (const float*)d_in[6];
    const float* b_phi     = (const float*)d_in[7];
    const float* W_gate    = (const float*)d_in[8];
    const float* b_gate    = (const float*)d_in[9];

    char* ws = (char*)d_ws;
    __hip_bfloat16* xb   = (__hip_bfloat16*)(ws);
    __hip_bfloat16* wb   = (__hip_bfloat16*)(ws + 33554432);
    __hip_bfloat16* raw5 = (__hip_bfloat16*)(ws + 44040192);
    float2* E     = (float2*)(ws);                // overlays xb (dead after GEMM)
    float2* carry = (float2*)(ws + 4194304);
    float2* apow  = (float2*)(ws + 8388608);
    float* out = (float*)d_out;

    convert_kernel<<<2048, 256, 0, stream>>>(x, W_psi, W_phi, W_gate, (ushort*)xb, (ushort*)wb);
    gemm_kernel<<<dim3(M_ / BM, N_ / BN), 256, 0, stream>>>(xb, wb, b_psi, b_phi, b_gate, raw5);
    apow_kernel<<<128, 256, 0, stream>>>(omega, log_gamma, dt, apow);
    scan1_kernel<<<dim3(CHUNKS, B_), 1024, 0, stream>>>(raw5, omega, log_gamma, dt, E);
    carry_kernel<<<B_ * D_, 128, 0, stream>>>(E, omega, log_gamma, dt, carry);
    finish_kernel<<<M_ / 4, 256, 0, stream>>>(raw5, carry, apow, out);
}